// Round 1
// baseline (5574.696 us; speedup 1.0000x reference)
//
#include <hip/hip_runtime.h>
#include <math.h>

#define N_AG 8192
#define M_NB 32
#define T_OBSN 8
#define T_PRD 12
#define HDIM 128
#define EDIM 64
#define G_AG 4
#define BLK 128

// packed weight offsets in d_ws (floats)
#define OFF_WIHE 0
#define OFF_WHHE 32768
#define OFF_WIHD 98304
#define OFF_WHHD 196608
#define OFF_SWT  262144
#define OFF_SWB  278528
#define PACK_FLOATS 286720

__device__ __forceinline__ float sigm(float x) { return 1.f / (1.f + expf(-x)); }

// Pack gate matrices (K,512) -> [k][j][4] (float4 per (k,j): the 4 gates), and
// sp_soc_W columns into float4-chunked-k layout.
__global__ void pack_weights(const float* __restrict__ encWih, const float* __restrict__ encWhh,
                             const float* __restrict__ decWih, const float* __restrict__ decWhh,
                             const float* __restrict__ sW, float* __restrict__ ws)
{
    for (int idx = blockIdx.x * blockDim.x + threadIdx.x; idx < PACK_FLOATS;
         idx += gridDim.x * blockDim.x) {
        float v; int t;
        if (idx < OFF_WHHE)      { t = idx;            int k = t >> 9, r = t & 511; v = encWih[k*512 + (r&3)*128 + (r>>2)]; }
        else if (idx < OFF_WIHD) { t = idx - OFF_WHHE; int k = t >> 9, r = t & 511; v = encWhh[k*512 + (r&3)*128 + (r>>2)]; }
        else if (idx < OFF_WHHD) { t = idx - OFF_WIHD; int k = t >> 9, r = t & 511; v = decWih[k*512 + (r&3)*128 + (r>>2)]; }
        else if (idx < OFF_SWT)  { t = idx - OFF_WHHD; int k = t >> 9, r = t & 511; v = decWhh[k*512 + (r&3)*128 + (r>>2)]; }
        else if (idx < OFF_SWB)  { t = idx - OFF_SWT;  int k0 = t >> 9, r = t & 511; v = sW[(4*k0 + (r&3))*128 + (r>>2)]; }
        else                     { t = idx - OFF_SWB;  int e0 = t >> 9, r = t & 511; v = sW[(128 + 4*e0 + (r&3))*128 + (r>>2)]; }
        ws[idx] = v;
    }
}

template<bool P>
__device__ __forceinline__ float4 ldGate(const float4* pk, const float* raw, int k, int j) {
    if constexpr (P) return pk[(k << 7) + j];
    else return make_float4(raw[k*512 + j], raw[k*512 + 128 + j],
                            raw[k*512 + 256 + j], raw[k*512 + 384 + j]);
}
template<bool P>
__device__ __forceinline__ float4 ldSWT(const float4* pk, const float* sW, int k0, int j) {
    if constexpr (P) return pk[(k0 << 7) + j];
    else return make_float4(sW[(4*k0+0)*128 + j], sW[(4*k0+1)*128 + j],
                            sW[(4*k0+2)*128 + j], sW[(4*k0+3)*128 + j]);
}
template<bool P>
__device__ __forceinline__ float4 ldSWB(const float4* pk, const float* sW, int e0, int j) {
    if constexpr (P) return pk[(e0 << 7) + j];
    else return make_float4(sW[(128+4*e0+0)*128 + j], sW[(128+4*e0+1)*128 + j],
                            sW[(128+4*e0+2)*128 + j], sW[(128+4*e0+3)*128 + j]);
}

template<bool PACKED>
__global__ __launch_bounds__(BLK)
void social_lstm(const float* __restrict__ obs,      // (N,8,2)
                 const float* __restrict__ nb_obs,   // (N,32,8,2)
                 const void*  __restrict__ nb_mask,  // (N,32) layout auto-detected
                 const float* __restrict__ weW, const float* __restrict__ web,
                 const float* __restrict__ encWih, const float* __restrict__ encWhh,
                 const float* __restrict__ encBih, const float* __restrict__ encBhh,
                 const float* __restrict__ pW,  const float* __restrict__ pb,
                 const float* __restrict__ sW,  const float* __restrict__ sb,
                 const float* __restrict__ wdW, const float* __restrict__ wdb,
                 const float* __restrict__ decWih, const float* __restrict__ decWhh,
                 const float* __restrict__ decBih, const float* __restrict__ decBhh,
                 const float* __restrict__ outW, const float* __restrict__ outB,
                 const float* __restrict__ wsp,
                 float* __restrict__ out)
{
    __shared__ __align__(16) float nbrel[G_AG][M_NB][T_OBSN][2]; // 8 KB
    __shared__ __align__(16) float focal[G_AG][T_OBSN][2];
    __shared__ __align__(16) float h_sh[G_AG][HDIM];
    __shared__ __align__(16) float emb_sh[G_AG][EDIM];
    __shared__ __align__(16) float pf_sh[G_AG][8][EDIM];        // 8 KB (nb chunk)
    __shared__ __align__(16) float soc_sh[G_AG][HDIM];
    __shared__ float rel_sh[G_AG][M_NB][2];
    __shared__ float valid_sh[G_AG][M_NB];
    __shared__ float origin_sh[G_AG][2];
    __shared__ float cur_sh[G_AG][2];
    __shared__ int   maskbits[G_AG];
    __shared__ int   det_flag;

    const int j  = threadIdx.x;
    const int n0 = blockIdx.x * G_AG;

    const float4* pWihE4 = (const float4*)(wsp + OFF_WIHE);
    const float4* pWhhE4 = (const float4*)(wsp + OFF_WHHE);
    const float4* pWihD4 = (const float4*)(wsp + OFF_WIHD);
    const float4* pWhhD4 = (const float4*)(wsp + OFF_WHHD);
    const float4* pSWT4  = (const float4*)(wsp + OFF_SWT);
    const float4* pSWB4  = (const float4*)(wsp + OFF_SWB);

    // ---- nb_mask layout detection (uniform across blocks: all scan words 0..255)
    if (j == 0) det_flag = 0;
    if (j < G_AG) maskbits[j] = 0;
    __syncthreads();
    {
        const unsigned* mw = (const unsigned*)nb_mask;
        unsigned w0 = mw[j], w1 = mw[BLK + j];
        int f = 0;
        if (w0 > 1u || w1 > 1u) f |= 1;                                   // not int32 0/1
        if ((w0 != 0u && w0 != 0x3F800000u) || (w1 != 0u && w1 != 0x3F800000u)) f |= 2; // not f32 0/1
        if (f) atomicOr(&det_flag, f);
    }
    __syncthreads();
    const int det = det_flag;
    {   // 128 threads = 4 agents x 32 neighbors
        int a = j >> 5, i = j & 31, gi = (n0 + a) * M_NB + i;
        int bit;
        if (!(det & 1))      bit = ((const int*)nb_mask)[gi] != 0;
        else if (!(det & 2)) bit = ((const float*)nb_mask)[gi] != 0.f;
        else                 bit = ((const unsigned char*)nb_mask)[gi] != 0;
        if (bit) atomicOr(&maskbits[a], 1 << i);
    }

    // ---- origin / focal (relative obs) / neighbor-relative tracks
    if (j < G_AG * 2) {
        int a = j >> 1, d = j & 1;
        origin_sh[a][d] = obs[(n0 + a) * 16 + 14 + d];
    }
    __syncthreads();
    if (j < G_AG * T_OBSN * 2) {   // 64
        int a = j >> 4, r = j & 15, t = r >> 1, d = r & 1;
        focal[a][t][d] = obs[(n0 + a) * 16 + t * 2 + d] - origin_sh[a][d];
    }
    for (int s = 0; s < 16; ++s) {
        int f = j + BLK * s;               // [0,2048)
        int a = f >> 9, r = f & 511;       // r = i*16 + t*2 + d
        int i = r >> 4, td = r & 15, d = r & 1;
        const float* base = nb_obs + ((n0 + a) * M_NB + i) * 16;
        nbrel[a][i][td >> 1][d] = base[td] - base[14 + d];
    }

    // per-thread fixed-e weights (e = j & 63) for pos_feat / embeddings
    const int ej = j & 63;
    const float pw0 = pW[ej],  pw1 = pW[EDIM + ej],  pbj_ = pb[ej];
    const float ew0 = weW[ej], ew1 = weW[EDIM + ej], ebj  = web[ej];
    const float dw0 = wdW[ej], dw1 = wdW[EDIM + ej], dbj  = wdb[ej];
    const float sbj = sb[j];
    const float bE[4] = { encBih[j] + encBhh[j], encBih[128 + j] + encBhh[128 + j],
                          encBih[256 + j] + encBhh[256 + j], encBih[384 + j] + encBhh[384 + j] };
    const float bD[4] = { decBih[j] + decBhh[j], decBih[128 + j] + decBhh[128 + j],
                          decBih[256 + j] + decBhh[256 + j], decBih[384 + j] + decBhh[384 + j] };

    float c_st[G_AG];
    #pragma unroll
    for (int a = 0; a < G_AG; ++a) { c_st[a] = 0.f; h_sh[a][j] = 0.f; }
    __syncthreads();

    // ===================== ENCODER =====================
    for (int t = 0; t < T_OBSN; ++t) {
        // phase 1: rel/valid per (a,i); embedding
        {
            int a = j >> 5, i = j & 31;
            float rx = nbrel[a][i][t][0] - focal[a][t][0];
            float ry = nbrel[a][i][t][1] - focal[a][t][1];
            rel_sh[a][i][0] = rx; rel_sh[a][i][1] = ry;
            bool v = (rx * rx + ry * ry <= 4.0f) && ((maskbits[a] >> i) & 1);
            valid_sh[a][i] = v ? 1.f : 0.f;
        }
        #pragma unroll
        for (int s2 = 0; s2 < 2; ++s2) {
            int a = (j >> 6) + 2 * s2;
            float x = focal[a][t][0] * ew0 + focal[a][t][1] * ew1 + ebj;
            emb_sh[a][ej] = fmaxf(x, 0.f);
        }
        __syncthreads();

        // phase 2 (reads old h): hp = sb + h@sW_top ; gates = bias + emb@Wih + h@Whh
        float hp[G_AG], gacc[G_AG][4];
        #pragma unroll
        for (int a = 0; a < G_AG; ++a) {
            hp[a] = sbj;
            #pragma unroll
            for (int g = 0; g < 4; ++g) gacc[a][g] = bE[g];
        }
        for (int k0 = 0; k0 < 32; ++k0) {
            float4 w = ldSWT<PACKED>(pSWT4, sW, k0, j);
            #pragma unroll
            for (int a = 0; a < G_AG; ++a) {
                float4 h4 = *(const float4*)&h_sh[a][4 * k0];
                hp[a] += h4.x * w.x + h4.y * w.y + h4.z * w.z + h4.w * w.w;
            }
        }
        for (int k0 = 0; k0 < 16; ++k0) {
            float4 w0_ = ldGate<PACKED>(pWihE4, encWih, 4 * k0 + 0, j);
            float4 w1_ = ldGate<PACKED>(pWihE4, encWih, 4 * k0 + 1, j);
            float4 w2_ = ldGate<PACKED>(pWihE4, encWih, 4 * k0 + 2, j);
            float4 w3_ = ldGate<PACKED>(pWihE4, encWih, 4 * k0 + 3, j);
            #pragma unroll
            for (int a = 0; a < G_AG; ++a) {
                float4 x4 = *(const float4*)&emb_sh[a][4 * k0];
                gacc[a][0] += x4.x * w0_.x + x4.y * w1_.x + x4.z * w2_.x + x4.w * w3_.x;
                gacc[a][1] += x4.x * w0_.y + x4.y * w1_.y + x4.z * w2_.y + x4.w * w3_.y;
                gacc[a][2] += x4.x * w0_.z + x4.y * w1_.z + x4.z * w2_.z + x4.w * w3_.z;
                gacc[a][3] += x4.x * w0_.w + x4.y * w1_.w + x4.z * w2_.w + x4.w * w3_.w;
            }
        }
        for (int k0 = 0; k0 < 32; ++k0) {
            float4 w0_ = ldGate<PACKED>(pWhhE4, encWhh, 4 * k0 + 0, j);
            float4 w1_ = ldGate<PACKED>(pWhhE4, encWhh, 4 * k0 + 1, j);
            float4 w2_ = ldGate<PACKED>(pWhhE4, encWhh, 4 * k0 + 2, j);
            float4 w3_ = ldGate<PACKED>(pWhhE4, encWhh, 4 * k0 + 3, j);
            #pragma unroll
            for (int a = 0; a < G_AG; ++a) {
                float4 x4 = *(const float4*)&h_sh[a][4 * k0];
                gacc[a][0] += x4.x * w0_.x + x4.y * w1_.x + x4.z * w2_.x + x4.w * w3_.x;
                gacc[a][1] += x4.x * w0_.y + x4.y * w1_.y + x4.z * w2_.y + x4.w * w3_.y;
                gacc[a][2] += x4.x * w0_.z + x4.y * w1_.z + x4.z * w2_.z + x4.w * w3_.z;
                gacc[a][3] += x4.x * w0_.w + x4.y * w1_.w + x4.z * w2_.w + x4.w * w3_.w;
            }
        }

        // social pooling over 4 chunks of 8 neighbors
        float m_soc[G_AG];
        #pragma unroll
        for (int a = 0; a < G_AG; ++a) m_soc[a] = -1e30f;
        for (int i0 = 0; i0 < M_NB; i0 += 8) {
            // (A) pos_feat for chunk into LDS
            #pragma unroll
            for (int s2 = 0; s2 < 16; ++s2) {
                int f = (j >> 6) + 2 * s2;       // [0,32)
                int a = f >> 3, il = f & 7, i = i0 + il;
                float rx = rel_sh[a][i][0], ry = rel_sh[a][i][1];
                pf_sh[a][il][ej] = fmaxf(rx * pw0 + ry * pw1 + pbj_, 0.f);
            }
            __syncthreads();
            // (B) z = hp + pf @ sW_bot ; fold masked max
            float acc[G_AG][8];
            #pragma unroll
            for (int a = 0; a < G_AG; ++a)
                #pragma unroll
                for (int il = 0; il < 8; ++il) acc[a][il] = hp[a];
            for (int e0 = 0; e0 < 16; ++e0) {
                float4 w = ldSWB<PACKED>(pSWB4, sW, e0, j);
                #pragma unroll
                for (int a = 0; a < G_AG; ++a)
                    #pragma unroll
                    for (int il = 0; il < 8; ++il) {
                        float4 p4 = *(const float4*)&pf_sh[a][il][4 * e0];
                        acc[a][il] += p4.x * w.x + p4.y * w.y + p4.z * w.z + p4.w * w.w;
                    }
            }
            #pragma unroll
            for (int a = 0; a < G_AG; ++a)
                #pragma unroll
                for (int il = 0; il < 8; ++il)
                    if (valid_sh[a][i0 + il] > 0.5f) m_soc[a] = fmaxf(m_soc[a], acc[a][il]);
            __syncthreads();
        }

        // LSTM cell + social injection; write new h
        #pragma unroll
        for (int a = 0; a < G_AG; ++a) {
            float ig = sigm(gacc[a][0]), fg = sigm(gacc[a][1]);
            float gg = tanhf(gacc[a][2]), og = sigm(gacc[a][3]);
            c_st[a] = fg * c_st[a] + ig * gg;
            float hl = og * tanhf(c_st[a]);
            h_sh[a][j] = hl + 0.3f * fmaxf(m_soc[a], 0.f);
        }
        // next iteration's phase-1 sync provides the h visibility barrier
    }
    __syncthreads();

    // ===================== DECODER =====================
    // hpE = h_enc @ sW_top (fixed over decoder steps)
    float hpE[G_AG];
    #pragma unroll
    for (int a = 0; a < G_AG; ++a) hpE[a] = 0.f;
    for (int k0 = 0; k0 < 32; ++k0) {
        float4 w = ldSWT<PACKED>(pSWT4, sW, k0, j);
        #pragma unroll
        for (int a = 0; a < G_AG; ++a) {
            float4 h4 = *(const float4*)&h_sh[a][4 * k0];
            hpE[a] += h4.x * w.x + h4.y * w.y + h4.z * w.z + h4.w * w.w;
        }
    }
    if (j < G_AG * 2) cur_sh[j >> 1][j & 1] = 0.f;
    __syncthreads();

    for (int st = 0; st < T_PRD; ++st) {
        // phase 1: pos_feat(-cur) and embedding(cur)
        #pragma unroll
        for (int s2 = 0; s2 < 2; ++s2) {
            int a = (j >> 6) + 2 * s2;
            float cx = cur_sh[a][0], cy = cur_sh[a][1];
            pf_sh[a][0][ej] = fmaxf(-(cx * pw0 + cy * pw1) + pbj_, 0.f);
            emb_sh[a][ej]   = fmaxf(cx * dw0 + cy * dw1 + dbj, 0.f);
        }
        __syncthreads();

        // phase 2: social = valid ? relu(hpE + pf@sW_bot + sb) : 0
        {
            float zz[G_AG];
            #pragma unroll
            for (int a = 0; a < G_AG; ++a) zz[a] = hpE[a] + sbj;
            for (int e0 = 0; e0 < 16; ++e0) {
                float4 w = ldSWB<PACKED>(pSWB4, sW, e0, j);
                #pragma unroll
                for (int a = 0; a < G_AG; ++a) {
                    float4 p4 = *(const float4*)&pf_sh[a][0][4 * e0];
                    zz[a] += p4.x * w.x + p4.y * w.y + p4.z * w.z + p4.w * w.w;
                }
            }
            #pragma unroll
            for (int a = 0; a < G_AG; ++a) {
                float cx = cur_sh[a][0], cy = cur_sh[a][1];
                bool v = (cx * cx + cy * cy <= 4.0f) && (maskbits[a] != 0);
                soc_sh[a][j] = v ? fmaxf(zz[a], 0.f) : 0.f;
            }
        }
        __syncthreads();

        // phase 3: gates = bias + [emb,social]@Wih + h@Whh ; LSTM update
        float gacc[G_AG][4];
        #pragma unroll
        for (int a = 0; a < G_AG; ++a)
            #pragma unroll
            for (int g = 0; g < 4; ++g) gacc[a][g] = bD[g];
        for (int k0 = 0; k0 < 16; ++k0) {
            float4 w0_ = ldGate<PACKED>(pWihD4, decWih, 4 * k0 + 0, j);
            float4 w1_ = ldGate<PACKED>(pWihD4, decWih, 4 * k0 + 1, j);
            float4 w2_ = ldGate<PACKED>(pWihD4, decWih, 4 * k0 + 2, j);
            float4 w3_ = ldGate<PACKED>(pWihD4, decWih, 4 * k0 + 3, j);
            #pragma unroll
            for (int a = 0; a < G_AG; ++a) {
                float4 x4 = *(const float4*)&emb_sh[a][4 * k0];
                gacc[a][0] += x4.x * w0_.x + x4.y * w1_.x + x4.z * w2_.x + x4.w * w3_.x;
                gacc[a][1] += x4.x * w0_.y + x4.y * w1_.y + x4.z * w2_.y + x4.w * w3_.y;
                gacc[a][2] += x4.x * w0_.z + x4.y * w1_.z + x4.z * w2_.z + x4.w * w3_.z;
                gacc[a][3] += x4.x * w0_.w + x4.y * w1_.w + x4.z * w2_.w + x4.w * w3_.w;
            }
        }
        for (int k0 = 0; k0 < 32; ++k0) {   // social rows of Wih (k = 64 + 4k0 + kk)
            float4 w0_ = ldGate<PACKED>(pWihD4, decWih, 64 + 4 * k0 + 0, j);
            float4 w1_ = ldGate<PACKED>(pWihD4, decWih, 64 + 4 * k0 + 1, j);
            float4 w2_ = ldGate<PACKED>(pWihD4, decWih, 64 + 4 * k0 + 2, j);
            float4 w3_ = ldGate<PACKED>(pWihD4, decWih, 64 + 4 * k0 + 3, j);
            #pragma unroll
            for (int a = 0; a < G_AG; ++a) {
                float4 x4 = *(const float4*)&soc_sh[a][4 * k0];
                gacc[a][0] += x4.x * w0_.x + x4.y * w1_.x + x4.z * w2_.x + x4.w * w3_.x;
                gacc[a][1] += x4.x * w0_.y + x4.y * w1_.y + x4.z * w2_.y + x4.w * w3_.y;
                gacc[a][2] += x4.x * w0_.z + x4.y * w1_.z + x4.z * w2_.z + x4.w * w3_.z;
                gacc[a][3] += x4.x * w0_.w + x4.y * w1_.w + x4.z * w2_.w + x4.w * w3_.w;
            }
        }
        for (int k0 = 0; k0 < 32; ++k0) {
            float4 w0_ = ldGate<PACKED>(pWhhD4, decWhh, 4 * k0 + 0, j);
            float4 w1_ = ldGate<PACKED>(pWhhD4, decWhh, 4 * k0 + 1, j);
            float4 w2_ = ldGate<PACKED>(pWhhD4, decWhh, 4 * k0 + 2, j);
            float4 w3_ = ldGate<PACKED>(pWhhD4, decWhh, 4 * k0 + 3, j);
            #pragma unroll
            for (int a = 0; a < G_AG; ++a) {
                float4 x4 = *(const float4*)&h_sh[a][4 * k0];
                gacc[a][0] += x4.x * w0_.x + x4.y * w1_.x + x4.z * w2_.x + x4.w * w3_.x;
                gacc[a][1] += x4.x * w0_.y + x4.y * w1_.y + x4.z * w2_.y + x4.w * w3_.y;
                gacc[a][2] += x4.x * w0_.z + x4.y * w1_.z + x4.z * w2_.z + x4.w * w3_.z;
                gacc[a][3] += x4.x * w0_.w + x4.y * w1_.w + x4.z * w2_.w + x4.w * w3_.w;
            }
        }
        float hnew[G_AG];
        #pragma unroll
        for (int a = 0; a < G_AG; ++a) {
            float ig = sigm(gacc[a][0]), fg = sigm(gacc[a][1]);
            float gg = tanhf(gacc[a][2]), og = sigm(gacc[a][3]);
            c_st[a] = fg * c_st[a] + ig * gg;
            hnew[a] = og * tanhf(c_st[a]);
        }
        __syncthreads();                 // all reads of old h done
        #pragma unroll
        for (int a = 0; a < G_AG; ++a) h_sh[a][j] = hnew[a];
        __syncthreads();

        // phase 4: outputs — 20 threads: (agent, out-channel)
        if (j < G_AG * 5) {
            int a = j / 5, p = j % 5;
            float r = outB[p];
            for (int k0 = 0; k0 < 32; ++k0) {
                float4 h4 = *(const float4*)&h_sh[a][4 * k0];
                r += h4.x * outW[(4 * k0 + 0) * 5 + p] + h4.y * outW[(4 * k0 + 1) * 5 + p]
                   + h4.z * outW[(4 * k0 + 2) * 5 + p] + h4.w * outW[(4 * k0 + 3) * 5 + p];
            }
            int n = n0 + a;
            if (p < 2) {
                cur_sh[a][p] = r;                                   // relative mu feeds next step
                out[n * (T_PRD * 2) + st * 2 + p] = r + origin_sh[a][p];
            } else if (p < 4) {
                float cl = fminf(fmaxf(r, -4.f), 4.f);
                out[N_AG * T_PRD * 2 + n * (T_PRD * 2) + st * 2 + (p - 2)] = expf(cl);
            } else {
                out[N_AG * T_PRD * 4 + n * T_PRD + st] = tanhf(r);
            }
        }
        __syncthreads();
    }
}

extern "C" void kernel_launch(void* const* d_in, const int* in_sizes, int n_in,
                              void* d_out, int out_size, void* d_ws, size_t ws_size,
                              hipStream_t stream) {
    const float* obs    = (const float*)d_in[0];
    const float* nb_obs = (const float*)d_in[1];
    const void*  nb_mask= d_in[2];
    const float* weW    = (const float*)d_in[3];
    const float* web    = (const float*)d_in[4];
    const float* encWih = (const float*)d_in[5];
    const float* encWhh = (const float*)d_in[6];
    const float* encBih = (const float*)d_in[7];
    const float* encBhh = (const float*)d_in[8];
    const float* pW     = (const float*)d_in[9];
    const float* pb     = (const float*)d_in[10];
    const float* sW     = (const float*)d_in[11];
    const float* sb     = (const float*)d_in[12];
    const float* wdW    = (const float*)d_in[13];
    const float* wdb    = (const float*)d_in[14];
    const float* decWih = (const float*)d_in[15];
    const float* decWhh = (const float*)d_in[16];
    const float* decBih = (const float*)d_in[17];
    const float* decBhh = (const float*)d_in[18];
    const float* outW   = (const float*)d_in[19];
    const float* outB   = (const float*)d_in[20];
    float* out = (float*)d_out;
    float* wsf = (float*)d_ws;

    const bool packed = ws_size >= (size_t)PACK_FLOATS * sizeof(float);
    const int grid = N_AG / G_AG;
    if (packed) {
        pack_weights<<<(PACK_FLOATS + 255) / 256, 256, 0, stream>>>(encWih, encWhh, decWih, decWhh, sW, wsf);
        social_lstm<true><<<grid, BLK, 0, stream>>>(obs, nb_obs, nb_mask, weW, web,
            encWih, encWhh, encBih, encBhh, pW, pb, sW, sb, wdW, wdb,
            decWih, decWhh, decBih, decBhh, outW, outB, wsf, out);
    } else {
        social_lstm<false><<<grid, BLK, 0, stream>>>(obs, nb_obs, nb_mask, weW, web,
            encWih, encWhh, encBih, encBhh, pW, pb, sW, sb, wdW, wdb,
            decWih, decWhh, decBih, decBhh, outW, outB, wsf, out);
    }
}

// Round 2
// 1825.417 us; speedup vs baseline: 3.0539x; 3.0539x over previous
//
#include <hip/hip_runtime.h>
#include <math.h>

#define N_AG 8192
#define M_NB 32
#define T_OBSN 8
#define T_PRD 12
#define HDIM 128
#define EDIM 64
#define G_AG 4
#define BLK 128

// packed weight offsets in d_ws (floats)
#define OFF_WIHE 0
#define OFF_WHHE 32768
#define OFF_WIHD 98304
#define OFF_WHHD 196608
#define OFF_SWT  262144
#define OFF_SWB  278528
#define PACK_FLOATS 286720

__device__ __forceinline__ float sigm(float x) { return 1.f / (1.f + expf(-x)); }

// Pack gate matrices (K,512) -> [k][j][4] (float4 per (k,j): the 4 gates), and
// sp_soc_W columns into float4-chunked-k layout.
__global__ void pack_weights(const float* __restrict__ encWih, const float* __restrict__ encWhh,
                             const float* __restrict__ decWih, const float* __restrict__ decWhh,
                             const float* __restrict__ sW, float* __restrict__ ws)
{
    for (int idx = blockIdx.x * blockDim.x + threadIdx.x; idx < PACK_FLOATS;
         idx += gridDim.x * blockDim.x) {
        float v; int t;
        if (idx < OFF_WHHE)      { t = idx;            int k = t >> 9, r = t & 511; v = encWih[k*512 + (r&3)*128 + (r>>2)]; }
        else if (idx < OFF_WIHD) { t = idx - OFF_WHHE; int k = t >> 9, r = t & 511; v = encWhh[k*512 + (r&3)*128 + (r>>2)]; }
        else if (idx < OFF_WHHD) { t = idx - OFF_WIHD; int k = t >> 9, r = t & 511; v = decWih[k*512 + (r&3)*128 + (r>>2)]; }
        else if (idx < OFF_SWT)  { t = idx - OFF_WHHD; int k = t >> 9, r = t & 511; v = decWhh[k*512 + (r&3)*128 + (r>>2)]; }
        else if (idx < OFF_SWB)  { t = idx - OFF_SWT;  int k0 = t >> 9, r = t & 511; v = sW[(4*k0 + (r&3))*128 + (r>>2)]; }
        else                     { t = idx - OFF_SWB;  int e0 = t >> 9, r = t & 511; v = sW[(128 + 4*e0 + (r&3))*128 + (r>>2)]; }
        ws[idx] = v;
    }
}

template<bool P>
__device__ __forceinline__ float4 ldGate(const float4* pk, const float* raw, int k, int j) {
    if constexpr (P) return pk[(k << 7) + j];
    else return make_float4(raw[k*512 + j], raw[k*512 + 128 + j],
                            raw[k*512 + 256 + j], raw[k*512 + 384 + j]);
}
template<bool P>
__device__ __forceinline__ float4 ldSWT(const float4* pk, const float* sW, int k0, int j) {
    if constexpr (P) return pk[(k0 << 7) + j];
    else return make_float4(sW[(4*k0+0)*128 + j], sW[(4*k0+1)*128 + j],
                            sW[(4*k0+2)*128 + j], sW[(4*k0+3)*128 + j]);
}
template<bool P>
__device__ __forceinline__ float4 ldSWB(const float4* pk, const float* sW, int e0, int j) {
    if constexpr (P) return pk[(e0 << 7) + j];
    else return make_float4(sW[(128+4*e0+0)*128 + j], sW[(128+4*e0+1)*128 + j],
                            sW[(128+4*e0+2)*128 + j], sW[(128+4*e0+3)*128 + j]);
}

template<bool PACKED>
__global__ __launch_bounds__(BLK, 3)
void social_lstm(const float* __restrict__ obs,      // (N,8,2)
                 const float* __restrict__ nb_obs,   // (N,32,8,2)
                 const void*  __restrict__ nb_mask,  // (N,32) layout auto-detected
                 const float* __restrict__ weW, const float* __restrict__ web,
                 const float* __restrict__ encWih, const float* __restrict__ encWhh,
                 const float* __restrict__ encBih, const float* __restrict__ encBhh,
                 const float* __restrict__ pW,  const float* __restrict__ pb,
                 const float* __restrict__ sW,  const float* __restrict__ sb,
                 const float* __restrict__ wdW, const float* __restrict__ wdb,
                 const float* __restrict__ decWih, const float* __restrict__ decWhh,
                 const float* __restrict__ decBih, const float* __restrict__ decBhh,
                 const float* __restrict__ outW, const float* __restrict__ outB,
                 const float* __restrict__ wsp,
                 float* __restrict__ out)
{
    __shared__ __align__(16) float nbrel[G_AG][M_NB][T_OBSN][2]; // 8 KB
    __shared__ __align__(16) float focal[G_AG][T_OBSN][2];
    __shared__ __align__(16) float h_sh[G_AG][HDIM];             // 2 KB
    __shared__ __align__(16) float emb_sh[G_AG][EDIM];           // 1 KB
    __shared__ __align__(16) float pf_sh[G_AG][4][EDIM];         // 4 KB (nb chunk of 4)
    __shared__ __align__(16) float soc_sh[G_AG][HDIM];           // 2 KB
    __shared__ float rel_sh[G_AG][M_NB][2];
    __shared__ float valid_sh[G_AG][M_NB];
    __shared__ float origin_sh[G_AG][2];
    __shared__ float cur_sh[G_AG][2];
    __shared__ int   maskbits[G_AG];
    __shared__ int   det_flag;

    const int j  = threadIdx.x;
    const int n0 = blockIdx.x * G_AG;

    const float4* pWihE4 = (const float4*)(wsp + OFF_WIHE);
    const float4* pWhhE4 = (const float4*)(wsp + OFF_WHHE);
    const float4* pWihD4 = (const float4*)(wsp + OFF_WIHD);
    const float4* pWhhD4 = (const float4*)(wsp + OFF_WHHD);
    const float4* pSWT4  = (const float4*)(wsp + OFF_SWT);
    const float4* pSWB4  = (const float4*)(wsp + OFF_SWB);

    // ---- nb_mask layout detection (uniform across blocks)
    if (j == 0) det_flag = 0;
    if (j < G_AG) maskbits[j] = 0;
    __syncthreads();
    {
        const unsigned* mw = (const unsigned*)nb_mask;
        unsigned w0 = mw[j], w1 = mw[BLK + j];
        int f = 0;
        if (w0 > 1u || w1 > 1u) f |= 1;                                   // not int32 0/1
        if ((w0 != 0u && w0 != 0x3F800000u) || (w1 != 0u && w1 != 0x3F800000u)) f |= 2; // not f32 0/1
        if (f) atomicOr(&det_flag, f);
    }
    __syncthreads();
    const int det = det_flag;
    {   // 128 threads = 4 agents x 32 neighbors
        int a = j >> 5, i = j & 31, gi = (n0 + a) * M_NB + i;
        int bit;
        if (!(det & 1))      bit = ((const int*)nb_mask)[gi] != 0;
        else if (!(det & 2)) bit = ((const float*)nb_mask)[gi] != 0.f;
        else                 bit = ((const unsigned char*)nb_mask)[gi] != 0;
        if (bit) atomicOr(&maskbits[a], 1 << i);
    }

    // ---- origin / focal (relative obs) / neighbor-relative tracks
    if (j < G_AG * 2) {
        int a = j >> 1, d = j & 1;
        origin_sh[a][d] = obs[(n0 + a) * 16 + 14 + d];
    }
    __syncthreads();
    if (j < G_AG * T_OBSN * 2) {   // 64
        int a = j >> 4, r = j & 15, t = r >> 1, d = r & 1;
        focal[a][t][d] = obs[(n0 + a) * 16 + t * 2 + d] - origin_sh[a][d];
    }
    #pragma unroll 1
    for (int s = 0; s < 16; ++s) {
        int f = j + BLK * s;               // [0,2048)
        int a = f >> 9, r = f & 511;       // r = i*16 + t*2 + d
        int i = r >> 4, td = r & 15, d = r & 1;
        const float* base = nb_obs + ((n0 + a) * M_NB + i) * 16;
        nbrel[a][i][td >> 1][d] = base[td] - base[14 + d];
    }

    // per-thread fixed-e weights (e = j & 63)
    const int ej = j & 63;
    const float pw0 = pW[ej],  pw1 = pW[EDIM + ej],  pbj_ = pb[ej];
    const float ew0 = weW[ej], ew1 = weW[EDIM + ej], ebj  = web[ej];
    const float dw0 = wdW[ej], dw1 = wdW[EDIM + ej], dbj  = wdb[ej];
    const float sbj = sb[j];
    const float bE[4] = { encBih[j] + encBhh[j], encBih[128 + j] + encBhh[128 + j],
                          encBih[256 + j] + encBhh[256 + j], encBih[384 + j] + encBhh[384 + j] };
    const float bD[4] = { decBih[j] + decBhh[j], decBih[128 + j] + decBhh[128 + j],
                          decBih[256 + j] + decBhh[256 + j], decBih[384 + j] + decBhh[384 + j] };

    float c_st[G_AG];
    #pragma unroll
    for (int a = 0; a < G_AG; ++a) { c_st[a] = 0.f; h_sh[a][j] = 0.f; }
    __syncthreads();

    // ===================== ENCODER =====================
    #pragma unroll 1
    for (int t = 0; t < T_OBSN; ++t) {
        // phase 1: rel/valid per (a,i); embedding
        {
            int a = j >> 5, i = j & 31;
            float rx = nbrel[a][i][t][0] - focal[a][t][0];
            float ry = nbrel[a][i][t][1] - focal[a][t][1];
            rel_sh[a][i][0] = rx; rel_sh[a][i][1] = ry;
            bool v = (rx * rx + ry * ry <= 4.0f) && ((maskbits[a] >> i) & 1);
            valid_sh[a][i] = v ? 1.f : 0.f;
        }
        #pragma unroll
        for (int s2 = 0; s2 < 2; ++s2) {
            int a = (j >> 6) + 2 * s2;
            float x = focal[a][t][0] * ew0 + focal[a][t][1] * ew1 + ebj;
            emb_sh[a][ej] = fmaxf(x, 0.f);
        }
        __syncthreads();

        // phase 2: hp = sb + h@sW_top (reads old h)
        float hp[G_AG];
        #pragma unroll
        for (int a = 0; a < G_AG; ++a) hp[a] = sbj;
        #pragma unroll 1
        for (int k0 = 0; k0 < 32; ++k0) {
            float4 w = ldSWT<PACKED>(pSWT4, sW, k0, j);
            #pragma unroll
            for (int a = 0; a < G_AG; ++a) {
                float4 h4 = *(const float4*)&h_sh[a][4 * k0];
                hp[a] += h4.x * w.x + h4.y * w.y + h4.z * w.z + h4.w * w.w;
            }
        }

        // phase 3: social pooling over 8 chunks of 4 neighbors (gacc NOT live here)
        float m_soc[G_AG];
        #pragma unroll
        for (int a = 0; a < G_AG; ++a) m_soc[a] = -1e30f;
        #pragma unroll 1
        for (int i0 = 0; i0 < M_NB; i0 += 4) {
            // (A) pos_feat for chunk into LDS: 16 (a,il) pairs x 64 e
            #pragma unroll
            for (int s2 = 0; s2 < 8; ++s2) {
                int p = (j >> 6) + 2 * s2;       // [0,16)
                int a = p >> 2, il = p & 3, i = i0 + il;
                float rx = rel_sh[a][i][0], ry = rel_sh[a][i][1];
                pf_sh[a][il][ej] = fmaxf(rx * pw0 + ry * pw1 + pbj_, 0.f);
            }
            __syncthreads();
            // (B) z = hp + pf @ sW_bot ; fold masked max
            float acc[G_AG][4];
            #pragma unroll
            for (int a = 0; a < G_AG; ++a)
                #pragma unroll
                for (int il = 0; il < 4; ++il) acc[a][il] = hp[a];
            #pragma unroll 1
            for (int e0 = 0; e0 < 16; ++e0) {
                float4 w = ldSWB<PACKED>(pSWB4, sW, e0, j);
                #pragma unroll
                for (int a = 0; a < G_AG; ++a)
                    #pragma unroll
                    for (int il = 0; il < 4; ++il) {
                        float4 p4 = *(const float4*)&pf_sh[a][il][4 * e0];
                        acc[a][il] += p4.x * w.x + p4.y * w.y + p4.z * w.z + p4.w * w.w;
                    }
            }
            #pragma unroll
            for (int a = 0; a < G_AG; ++a)
                #pragma unroll
                for (int il = 0; il < 4; ++il) {
                    bool v = valid_sh[a][i0 + il] > 0.5f;
                    m_soc[a] = v ? fmaxf(m_soc[a], acc[a][il]) : m_soc[a];
                }
            __syncthreads();
        }

        // phase 4: gates = bias + emb@Wih + h@Whh (reads old h)
        float gacc[G_AG][4];
        #pragma unroll
        for (int a = 0; a < G_AG; ++a)
            #pragma unroll
            for (int g = 0; g < 4; ++g) gacc[a][g] = bE[g];
        #pragma unroll 1
        for (int k0 = 0; k0 < 16; ++k0) {
            float4 w0_ = ldGate<PACKED>(pWihE4, encWih, 4 * k0 + 0, j);
            float4 w1_ = ldGate<PACKED>(pWihE4, encWih, 4 * k0 + 1, j);
            float4 w2_ = ldGate<PACKED>(pWihE4, encWih, 4 * k0 + 2, j);
            float4 w3_ = ldGate<PACKED>(pWihE4, encWih, 4 * k0 + 3, j);
            #pragma unroll
            for (int a = 0; a < G_AG; ++a) {
                float4 x4 = *(const float4*)&emb_sh[a][4 * k0];
                gacc[a][0] += x4.x * w0_.x + x4.y * w1_.x + x4.z * w2_.x + x4.w * w3_.x;
                gacc[a][1] += x4.x * w0_.y + x4.y * w1_.y + x4.z * w2_.y + x4.w * w3_.y;
                gacc[a][2] += x4.x * w0_.z + x4.y * w1_.z + x4.z * w2_.z + x4.w * w3_.z;
                gacc[a][3] += x4.x * w0_.w + x4.y * w1_.w + x4.z * w2_.w + x4.w * w3_.w;
            }
        }
        #pragma unroll 1
        for (int k0 = 0; k0 < 32; ++k0) {
            float4 w0_ = ldGate<PACKED>(pWhhE4, encWhh, 4 * k0 + 0, j);
            float4 w1_ = ldGate<PACKED>(pWhhE4, encWhh, 4 * k0 + 1, j);
            float4 w2_ = ldGate<PACKED>(pWhhE4, encWhh, 4 * k0 + 2, j);
            float4 w3_ = ldGate<PACKED>(pWhhE4, encWhh, 4 * k0 + 3, j);
            #pragma unroll
            for (int a = 0; a < G_AG; ++a) {
                float4 x4 = *(const float4*)&h_sh[a][4 * k0];
                gacc[a][0] += x4.x * w0_.x + x4.y * w1_.x + x4.z * w2_.x + x4.w * w3_.x;
                gacc[a][1] += x4.x * w0_.y + x4.y * w1_.y + x4.z * w2_.y + x4.w * w3_.y;
                gacc[a][2] += x4.x * w0_.z + x4.y * w1_.z + x4.z * w2_.z + x4.w * w3_.z;
                gacc[a][3] += x4.x * w0_.w + x4.y * w1_.w + x4.z * w2_.w + x4.w * w3_.w;
            }
        }

        // phase 5: all h reads done
        __syncthreads();

        // phase 6: LSTM cell + social injection; write new h
        #pragma unroll
        for (int a = 0; a < G_AG; ++a) {
            float ig = sigm(gacc[a][0]), fg = sigm(gacc[a][1]);
            float gg = tanhf(gacc[a][2]), og = sigm(gacc[a][3]);
            c_st[a] = fg * c_st[a] + ig * gg;
            float hl = og * tanhf(c_st[a]);
            h_sh[a][j] = hl + 0.3f * fmaxf(m_soc[a], 0.f);
        }
        // next iteration's phase-1 sync provides the h visibility barrier
    }
    __syncthreads();

    // ===================== DECODER =====================
    // hpE = h_enc @ sW_top (fixed over decoder steps)
    float hpE[G_AG];
    #pragma unroll
    for (int a = 0; a < G_AG; ++a) hpE[a] = 0.f;
    #pragma unroll 1
    for (int k0 = 0; k0 < 32; ++k0) {
        float4 w = ldSWT<PACKED>(pSWT4, sW, k0, j);
        #pragma unroll
        for (int a = 0; a < G_AG; ++a) {
            float4 h4 = *(const float4*)&h_sh[a][4 * k0];
            hpE[a] += h4.x * w.x + h4.y * w.y + h4.z * w.z + h4.w * w.w;
        }
    }
    if (j < G_AG * 2) cur_sh[j >> 1][j & 1] = 0.f;
    __syncthreads();

    #pragma unroll 1
    for (int st = 0; st < T_PRD; ++st) {
        // phase 1: pos_feat(-cur) and embedding(cur)
        #pragma unroll
        for (int s2 = 0; s2 < 2; ++s2) {
            int a = (j >> 6) + 2 * s2;
            float cx = cur_sh[a][0], cy = cur_sh[a][1];
            pf_sh[a][0][ej] = fmaxf(-(cx * pw0 + cy * pw1) + pbj_, 0.f);
            emb_sh[a][ej]   = fmaxf(cx * dw0 + cy * dw1 + dbj, 0.f);
        }
        __syncthreads();

        // phase 2: social = valid ? relu(hpE + pf@sW_bot + sb) : 0
        {
            float zz[G_AG];
            #pragma unroll
            for (int a = 0; a < G_AG; ++a) zz[a] = hpE[a] + sbj;
            #pragma unroll 1
            for (int e0 = 0; e0 < 16; ++e0) {
                float4 w = ldSWB<PACKED>(pSWB4, sW, e0, j);
                #pragma unroll
                for (int a = 0; a < G_AG; ++a) {
                    float4 p4 = *(const float4*)&pf_sh[a][0][4 * e0];
                    zz[a] += p4.x * w.x + p4.y * w.y + p4.z * w.z + p4.w * w.w;
                }
            }
            #pragma unroll
            for (int a = 0; a < G_AG; ++a) {
                float cx = cur_sh[a][0], cy = cur_sh[a][1];
                bool v = (cx * cx + cy * cy <= 4.0f) && (maskbits[a] != 0);
                soc_sh[a][j] = v ? fmaxf(zz[a], 0.f) : 0.f;
            }
        }
        __syncthreads();

        // phase 3: gates = bias + [emb,social]@Wih + h@Whh ; LSTM update
        float gacc[G_AG][4];
        #pragma unroll
        for (int a = 0; a < G_AG; ++a)
            #pragma unroll
            for (int g = 0; g < 4; ++g) gacc[a][g] = bD[g];
        #pragma unroll 1
        for (int k0 = 0; k0 < 16; ++k0) {
            float4 w0_ = ldGate<PACKED>(pWihD4, decWih, 4 * k0 + 0, j);
            float4 w1_ = ldGate<PACKED>(pWihD4, decWih, 4 * k0 + 1, j);
            float4 w2_ = ldGate<PACKED>(pWihD4, decWih, 4 * k0 + 2, j);
            float4 w3_ = ldGate<PACKED>(pWihD4, decWih, 4 * k0 + 3, j);
            #pragma unroll
            for (int a = 0; a < G_AG; ++a) {
                float4 x4 = *(const float4*)&emb_sh[a][4 * k0];
                gacc[a][0] += x4.x * w0_.x + x4.y * w1_.x + x4.z * w2_.x + x4.w * w3_.x;
                gacc[a][1] += x4.x * w0_.y + x4.y * w1_.y + x4.z * w2_.y + x4.w * w3_.y;
                gacc[a][2] += x4.x * w0_.z + x4.y * w1_.z + x4.z * w2_.z + x4.w * w3_.z;
                gacc[a][3] += x4.x * w0_.w + x4.y * w1_.w + x4.z * w2_.w + x4.w * w3_.w;
            }
        }
        #pragma unroll 1
        for (int k0 = 0; k0 < 32; ++k0) {   // social rows of Wih (k = 64 + 4k0 + kk)
            float4 w0_ = ldGate<PACKED>(pWihD4, decWih, 64 + 4 * k0 + 0, j);
            float4 w1_ = ldGate<PACKED>(pWihD4, decWih, 64 + 4 * k0 + 1, j);
            float4 w2_ = ldGate<PACKED>(pWihD4, decWih, 64 + 4 * k0 + 2, j);
            float4 w3_ = ldGate<PACKED>(pWihD4, decWih, 64 + 4 * k0 + 3, j);
            #pragma unroll
            for (int a = 0; a < G_AG; ++a) {
                float4 x4 = *(const float4*)&soc_sh[a][4 * k0];
                gacc[a][0] += x4.x * w0_.x + x4.y * w1_.x + x4.z * w2_.x + x4.w * w3_.x;
                gacc[a][1] += x4.x * w0_.y + x4.y * w1_.y + x4.z * w2_.y + x4.w * w3_.y;
                gacc[a][2] += x4.x * w0_.z + x4.y * w1_.z + x4.z * w2_.z + x4.w * w3_.z;
                gacc[a][3] += x4.x * w0_.w + x4.y * w1_.w + x4.z * w2_.w + x4.w * w3_.w;
            }
        }
        #pragma unroll 1
        for (int k0 = 0; k0 < 32; ++k0) {
            float4 w0_ = ldGate<PACKED>(pWhhD4, decWhh, 4 * k0 + 0, j);
            float4 w1_ = ldGate<PACKED>(pWhhD4, decWhh, 4 * k0 + 1, j);
            float4 w2_ = ldGate<PACKED>(pWhhD4, decWhh, 4 * k0 + 2, j);
            float4 w3_ = ldGate<PACKED>(pWhhD4, decWhh, 4 * k0 + 3, j);
            #pragma unroll
            for (int a = 0; a < G_AG; ++a) {
                float4 x4 = *(const float4*)&h_sh[a][4 * k0];
                gacc[a][0] += x4.x * w0_.x + x4.y * w1_.x + x4.z * w2_.x + x4.w * w3_.x;
                gacc[a][1] += x4.x * w0_.y + x4.y * w1_.y + x4.z * w2_.y + x4.w * w3_.y;
                gacc[a][2] += x4.x * w0_.z + x4.y * w1_.z + x4.z * w2_.z + x4.w * w3_.z;
                gacc[a][3] += x4.x * w0_.w + x4.y * w1_.w + x4.z * w2_.w + x4.w * w3_.w;
            }
        }
        float hnew[G_AG];
        #pragma unroll
        for (int a = 0; a < G_AG; ++a) {
            float ig = sigm(gacc[a][0]), fg = sigm(gacc[a][1]);
            float gg = tanhf(gacc[a][2]), og = sigm(gacc[a][3]);
            c_st[a] = fg * c_st[a] + ig * gg;
            hnew[a] = og * tanhf(c_st[a]);
        }
        __syncthreads();                 // all reads of old h done
        #pragma unroll
        for (int a = 0; a < G_AG; ++a) h_sh[a][j] = hnew[a];
        __syncthreads();

        // phase 4: outputs — 20 threads: (agent, out-channel)
        if (j < G_AG * 5) {
            int a = j / 5, p = j % 5;
            float r = outB[p];
            #pragma unroll 1
            for (int k0 = 0; k0 < 32; ++k0) {
                float4 h4 = *(const float4*)&h_sh[a][4 * k0];
                r += h4.x * outW[(4 * k0 + 0) * 5 + p] + h4.y * outW[(4 * k0 + 1) * 5 + p]
                   + h4.z * outW[(4 * k0 + 2) * 5 + p] + h4.w * outW[(4 * k0 + 3) * 5 + p];
            }
            int n = n0 + a;
            if (p < 2) {
                cur_sh[a][p] = r;                                   // relative mu feeds next step
                out[n * (T_PRD * 2) + st * 2 + p] = r + origin_sh[a][p];
            } else if (p < 4) {
                float cl = fminf(fmaxf(r, -4.f), 4.f);
                out[N_AG * T_PRD * 2 + n * (T_PRD * 2) + st * 2 + (p - 2)] = expf(cl);
            } else {
                out[N_AG * T_PRD * 4 + n * T_PRD + st] = tanhf(r);
            }
        }
        __syncthreads();
    }
}

extern "C" void kernel_launch(void* const* d_in, const int* in_sizes, int n_in,
                              void* d_out, int out_size, void* d_ws, size_t ws_size,
                              hipStream_t stream) {
    const float* obs    = (const float*)d_in[0];
    const float* nb_obs = (const float*)d_in[1];
    const void*  nb_mask= d_in[2];
    const float* weW    = (const float*)d_in[3];
    const float* web    = (const float*)d_in[4];
    const float* encWih = (const float*)d_in[5];
    const float* encWhh = (const float*)d_in[6];
    const float* encBih = (const float*)d_in[7];
    const float* encBhh = (const float*)d_in[8];
    const float* pW     = (const float*)d_in[9];
    const float* pb     = (const float*)d_in[10];
    const float* sW     = (const float*)d_in[11];
    const float* sb     = (const float*)d_in[12];
    const float* wdW    = (const float*)d_in[13];
    const float* wdb    = (const float*)d_in[14];
    const float* decWih = (const float*)d_in[15];
    const float* decWhh = (const float*)d_in[16];
    const float* decBih = (const float*)d_in[17];
    const float* decBhh = (const float*)d_in[18];
    const float* outW   = (const float*)d_in[19];
    const float* outB   = (const float*)d_in[20];
    float* out = (float*)d_out;
    float* wsf = (float*)d_ws;

    const bool packed = ws_size >= (size_t)PACK_FLOATS * sizeof(float);
    const int grid = N_AG / G_AG;
    if (packed) {
        pack_weights<<<(PACK_FLOATS + 255) / 256, 256, 0, stream>>>(encWih, encWhh, decWih, decWhh, sW, wsf);
        social_lstm<true><<<grid, BLK, 0, stream>>>(obs, nb_obs, nb_mask, weW, web,
            encWih, encWhh, encBih, encBhh, pW, pb, sW, sb, wdW, wdb,
            decWih, decWhh, decBih, decBhh, outW, outB, wsf, out);
    } else {
        social_lstm<false><<<grid, BLK, 0, stream>>>(obs, nb_obs, nb_mask, weW, web,
            encWih, encWhh, encBih, encBhh, pW, pb, sW, sb, wdW, wdb,
            decWih, decWhh, decBih, decBhh, outW, outB, wsf, out);
    }
}

// Round 4
// 857.865 us; speedup vs baseline: 6.4983x; 2.1279x over previous
//
#include <hip/hip_runtime.h>
#include <math.h>

typedef short bf16x8 __attribute__((ext_vector_type(8)));
typedef float f32x4  __attribute__((ext_vector_type(4)));

#define N_AG 8192
#define GA   16
#define BLK  256
#define TOB  8
#define TPR  12

// packed bf16 weight regions (offsets in shorts, inside d_ws)
#define PK_ENC 0
#define PK_DEC 98304            // + 6*32*512  (encoder gates)
#define PK_WB  262144           // +10*32*512  (decoder gates)
#define PK_WT  270336           // + 2*8*512   (sW pos-feat rows 128..191)
#define PK_TOT 286720           // + 4*8*512   (sW h rows 0..127)

__device__ __forceinline__ unsigned short f2bf(float f) {
    unsigned u = __float_as_uint(f);
    return (unsigned short)((u + 0x7FFFu + ((u >> 16) & 1u)) >> 16);   // RNE
}
__device__ __forceinline__ float bf2f(unsigned short s) {
    return __uint_as_float(((unsigned)s) << 16);
}
__device__ __forceinline__ float sigm(float x) { return 1.f / (1.f + __expf(-x)); }
__device__ __forceinline__ float tanhp(float x) {
    x = fminf(fmaxf(x, -15.f), 15.f);
    float e = __expf(2.f * x);
    return (e - 1.f) / (e + 1.f);
}

// Pack gate/social weights into per-MFMA-fragment bf16 blobs:
// frag(ks,nt) = 64 lanes x 8 shorts; element (l,i) = W[k][col],
// k = ks*32 + (l>>4)*8 + i, col = (nt>>3)*128 + (nt&7)*16 + (l&15)   (gates)
__global__ void pack_w(const float* __restrict__ eWih, const float* __restrict__ eWhh,
                       const float* __restrict__ dWih, const float* __restrict__ dWhh,
                       const float* __restrict__ sW, unsigned short* __restrict__ pk)
{
    for (int idx = blockIdx.x * blockDim.x + threadIdx.x; idx < PK_TOT;
         idx += gridDim.x * blockDim.x) {
        float v;
        if (idx < PK_DEC) {                       // encoder gates: ks 0-1 emb, 2-5 h
            int ks = idx >> 14, rem = idx & 16383;
            int nt = rem >> 9, l = (rem >> 3) & 63, i = rem & 7;
            int klo = ((l >> 4) << 3) + i;
            int col = (nt >> 3) * 128 + (nt & 7) * 16 + (l & 15);
            v = (ks < 2) ? eWih[(ks * 32 + klo) * 512 + col]
                         : eWhh[((ks - 2) * 32 + klo) * 512 + col];
        } else if (idx < PK_WB) {                 // decoder gates: ks 0-1 emb, 2-5 soc, 6-9 h
            int t = idx - PK_DEC;
            int ks = t >> 14, rem = t & 16383;
            int nt = rem >> 9, l = (rem >> 3) & 63, i = rem & 7;
            int klo = ((l >> 4) << 3) + i;
            int col = (nt >> 3) * 128 + (nt & 7) * 16 + (l & 15);
            if (ks < 2)      v = dWih[(ks * 32 + klo) * 512 + col];
            else if (ks < 6) v = dWih[(64 + (ks - 2) * 32 + klo) * 512 + col];
            else             v = dWhh[((ks - 6) * 32 + klo) * 512 + col];
        } else if (idx < PK_WT) {                 // Wb = sW rows 128..191 (pos-feat part), ks<2
            int t = idx - PK_WB;
            int ks = t >> 12, rem = t & 4095;
            int nt = rem >> 9, l = (rem >> 3) & 63, i = rem & 7;
            int klo = ((l >> 4) << 3) + i;
            v = sW[(128 + ks * 32 + klo) * 128 + nt * 16 + (l & 15)];
        } else {                                  // WT = sW rows 0..127 (h part), ks<4
            int t = idx - PK_WT;
            int ks = t >> 12, rem = t & 4095;
            int nt = rem >> 9, l = (rem >> 3) & 63, i = rem & 7;
            int klo = ((l >> 4) << 3) + i;
            v = sW[(ks * 32 + klo) * 128 + nt * 16 + (l & 15)];
        }
        pk[idx] = f2bf(v);
    }
}

__global__ __launch_bounds__(BLK, 2)
void slstm(const float* __restrict__ obs, const float* __restrict__ nb_obs,
           const void* __restrict__ nb_mask,
           const float* __restrict__ weW, const float* __restrict__ web,
           const float* __restrict__ eBih, const float* __restrict__ eBhh,
           const float* __restrict__ pW, const float* __restrict__ pb,
           const float* __restrict__ sb,
           const float* __restrict__ wdW, const float* __restrict__ wdb,
           const float* __restrict__ dBih, const float* __restrict__ dBhh,
           const float* __restrict__ outW, const float* __restrict__ outB,
           const unsigned short* __restrict__ pk,
           float* __restrict__ out)
{
    __shared__ __align__(16) float obsrel[TOB][GA][2];
    __shared__ float origin[GA][2];
    __shared__ __align__(16) float nblast[GA][32][2];
    __shared__ __align__(16) float rel2[GA][32][2];
    __shared__ unsigned vmask[GA];
    __shared__ int maskb[GA];
    __shared__ int detf;
    __shared__ __align__(16) short hbf[2][GA * 128];   // bf16 h, XOR-swizzled, ping-pong
    __shared__ __align__(16) short embb[GA * 64];      // bf16 emb, swizzled
    __shared__ __align__(16) short socb[GA * 128];     // bf16 decoder social, swizzled
    __shared__ __align__(16) short pfdb[GA * 64];      // bf16 decoder pos_feat, swizzled
    __shared__ float cur[GA][2];

    const int j    = threadIdx.x;
    const int lane = j & 63;
    const int w    = j >> 6;          // wave 0..3, owns hidx [32w, 32w+32)
    const int q    = lane >> 4;
    const int r16  = lane & 15;
    const int n0   = blockIdx.x * GA;

    // ---------- init: mask detection / static loads ----------
    if (j < GA) maskb[j] = 0;
    if (j == 0) detf = 0;
    __syncthreads();
    {
        const unsigned* mw = (const unsigned*)nb_mask;
        unsigned w0 = mw[j], w1 = mw[BLK + j];
        int f = 0;
        if (w0 > 1u || w1 > 1u) f |= 1;
        if ((w0 != 0u && w0 != 0x3F800000u) || (w1 != 0u && w1 != 0x3F800000u)) f |= 2;
        if (f) atomicOr(&detf, f);
    }
    __syncthreads();
    const int det = detf;
    #pragma unroll
    for (int s = 0; s < 2; ++s) {
        int p = j + s * BLK, a = p >> 5, i2 = p & 31, gi = (n0 + a) * 32 + i2;
        int bit;
        if (!(det & 1))      bit = ((const int*)nb_mask)[gi] != 0;
        else if (!(det & 2)) bit = (((const float*)nb_mask)[gi] != 0.f);
        else                 bit = ((const unsigned char*)nb_mask)[gi] != 0;
        if (bit) atomicOr(&maskb[a], 1 << i2);
    }
    if (j < 128) {
        int t = j >> 4, a = j & 15;
        float o0 = obs[(n0 + a) * 16 + 14], o1 = obs[(n0 + a) * 16 + 15];
        obsrel[t][a][0] = obs[(n0 + a) * 16 + t * 2]     - o0;
        obsrel[t][a][1] = obs[(n0 + a) * 16 + t * 2 + 1] - o1;
        if (t == 0) { origin[a][0] = o0; origin[a][1] = o1; }
    }
    #pragma unroll
    for (int s = 0; s < 2; ++s) {
        int p = j + s * BLK, a = p >> 5, i2 = p & 31;
        const float* nb = nb_obs + ((size_t)((n0 + a) * 32 + i2)) * 16 + 14;
        nblast[a][i2][0] = nb[0];
        nblast[a][i2][1] = nb[1];
    }
    ((int4*)hbf)[j] = make_int4(0, 0, 0, 0);   // zero h buffer 0 (exactly 4 KB)

    // per-lane constants
    float pc0[16], pc1[16], pcb[16];            // pos_feat weights for this lane's e-set
    #pragma unroll
    for (int ks = 0; ks < 2; ++ks)
        #pragma unroll
        for (int i = 0; i < 8; ++i) {
            int e = ks * 32 + q * 8 + i;
            pc0[ks * 8 + i] = pW[e];
            pc1[ks * 8 + i] = pW[64 + e];
            pcb[ks * 8 + i] = pb[e];
        }
    const float ew0 = weW[lane], ew1 = weW[64 + lane], ebv = web[lane];
    const float dw0 = wdW[lane], dw1 = wdW[64 + lane], dbv = wdb[lane];
    const float pwa = pW[lane], pwc = pW[64 + lane], pbb = pb[lane];
    float sbv[2];
    #pragma unroll
    for (int hh = 0; hh < 2; ++hh) sbv[hh] = sb[(2 * w + hh) * 16 + r16];
    float bG[2][4];
    #pragma unroll
    for (int hh = 0; hh < 2; ++hh)
        #pragma unroll
        for (int g = 0; g < 4; ++g) {
            int col = g * 128 + (2 * w + hh) * 16 + r16;
            bG[hh][g] = eBih[col] + eBhh[col];
        }
    const bf16x8* pkE = (const bf16x8*)(pk + PK_ENC);
    const bf16x8* pkD = (const bf16x8*)(pk + PK_DEC);
    const bf16x8* pkB = (const bf16x8*)(pk + PK_WB);
    const bf16x8* pkT = (const bf16x8*)(pk + PK_WT);
    bf16x8 wbf[2][2];                            // social Wb fragments, held in regs
    #pragma unroll
    for (int ks = 0; ks < 2; ++ks)
        #pragma unroll
        for (int hh = 0; hh < 2; ++hh)
            wbf[ks][hh] = pkB[(ks * 8 + 2 * w + hh) * 64 + lane];

    float cst[2][4];                             // cell state: (hidx=2w+hh, agent=q*4+rg)
    #pragma unroll
    for (int hh = 0; hh < 2; ++hh)
        #pragma unroll
        for (int rg = 0; rg < 4; ++rg) cst[hh][rg] = 0.f;

    const f32x4 zz4 = {0.f, 0.f, 0.f, 0.f};
    int pp = 0;
    __syncthreads();

    // ===================== ENCODER =====================
    #pragma unroll 1
    for (int t = 0; t < TOB; ++t) {
        // ---- phase A: rel/valid + emb ----
        #pragma unroll
        for (int s = 0; s < 2; ++s) {
            int p = j + s * BLK, a = p >> 5, i2 = p & 31;
            const float* nb = nb_obs + ((size_t)((n0 + a) * 32 + i2)) * 16 + t * 2;
            float rx = nb[0] - nblast[a][i2][0] - obsrel[t][a][0];
            float ry = nb[1] - nblast[a][i2][1] - obsrel[t][a][1];
            rel2[a][i2][0] = rx; rel2[a][i2][1] = ry;
            bool ok = (rx * rx + ry * ry <= 4.f) && ((maskb[a] >> i2) & 1);
            unsigned long long b = __ballot(ok);
            if ((lane & 31) == 0) vmask[a] = (unsigned)(b >> (lane & 32));
        }
        #pragma unroll
        for (int s2 = 0; s2 < 4; ++s2) {
            int a = w + s2 * 4;
            float x = fmaxf(obsrel[t][a][0] * ew0 + obsrel[t][a][1] * ew1 + ebv, 0.f);
            *(short*)((char*)embb + a * 128 + ((lane * 2) ^ ((a & 7) << 4))) = (short)f2bf(x);
        }
        __syncthreads();

        // ---- phase B ----
        const short* hb = hbf[pp];
        short* hw = hbf[pp ^ 1];

        // hp = h @ WT   (C rows = agents)
        f32x4 hpA[2] = {zz4, zz4};
        #pragma unroll
        for (int ks = 0; ks < 4; ++ks) {
            bf16x8 af = *(const bf16x8*)((const char*)hb + r16 * 256 +
                          (((ks * 32 + q * 8) * 2) ^ ((r16 & 7) << 4)));
            #pragma unroll
            for (int hh = 0; hh < 2; ++hh) {
                bf16x8 bfr = pkT[(ks * 8 + 2 * w + hh) * 64 + lane];
                hpA[hh] = __builtin_amdgcn_mfma_f32_16x16x32_bf16(af, bfr, hpA[hh], 0, 0, 0);
            }
        }

        // social: per agent, A (pos_feat) computed in regs, masked max over 32 nb
        float ms[2][4];
        #pragma unroll
        for (int hh = 0; hh < 2; ++hh)
            #pragma unroll
            for (int rg = 0; rg < 4; ++rg) ms[hh][rg] = -3e38f;
        #pragma unroll 1
        for (int a4 = 0; a4 < 4; ++a4) {
            #pragma unroll
            for (int ar = 0; ar < 4; ++ar) {
                int a = a4 * 4 + ar;
                unsigned vb = vmask[a];
                float ml0 = -3e38f, ml1 = -3e38f;
                #pragma unroll
                for (int Mt = 0; Mt < 2; ++Mt) {
                    float rx = rel2[a][Mt * 16 + r16][0];
                    float ry = rel2[a][Mt * 16 + r16][1];
                    f32x4 ac0 = zz4, ac1 = zz4;
                    #pragma unroll
                    for (int ks = 0; ks < 2; ++ks) {
                        bf16x8 af;
                        #pragma unroll
                        for (int i = 0; i < 8; ++i) {
                            float v = fmaxf(fmaf(ry, pc1[ks * 8 + i],
                                          fmaf(rx, pc0[ks * 8 + i], pcb[ks * 8 + i])), 0.f);
                            af[i] = (short)f2bf(v);
                        }
                        ac0 = __builtin_amdgcn_mfma_f32_16x16x32_bf16(af, wbf[ks][0], ac0, 0, 0, 0);
                        ac1 = __builtin_amdgcn_mfma_f32_16x16x32_bf16(af, wbf[ks][1], ac1, 0, 0, 0);
                    }
                    #pragma unroll
                    for (int rg = 0; rg < 4; ++rg) {
                        int inb = Mt * 16 + q * 4 + rg;
                        bool ok = (vb >> inb) & 1;
                        ml0 = fmaxf(ml0, ok ? ac0[rg] : -3e38f);
                        ml1 = fmaxf(ml1, ok ? ac1[rg] : -3e38f);
                    }
                }
                ml0 = fmaxf(ml0, __shfl_xor(ml0, 16));
                ml0 = fmaxf(ml0, __shfl_xor(ml0, 32));
                ml1 = fmaxf(ml1, __shfl_xor(ml1, 16));
                ml1 = fmaxf(ml1, __shfl_xor(ml1, 32));
                bool keep = (q == a4);
                ms[0][ar] = keep ? ml0 : ms[0][ar];
                ms[1][ar] = keep ? ml1 : ms[1][ar];
            }
        }

        // gates = [emb | h] @ W   (C rows = agents, cols = this wave's 2 hidx-blocks x 4 gates)
        bf16x8 gA[6];
        #pragma unroll
        for (int ks = 0; ks < 2; ++ks)
            gA[ks] = *(const bf16x8*)((const char*)embb + r16 * 128 +
                       (((ks * 32 + q * 8) * 2) ^ ((r16 & 7) << 4)));
        #pragma unroll
        for (int ks = 0; ks < 4; ++ks)
            gA[2 + ks] = *(const bf16x8*)((const char*)hb + r16 * 256 +
                       (((ks * 32 + q * 8) * 2) ^ ((r16 & 7) << 4)));
        f32x4 ag[2][4];
        #pragma unroll
        for (int hh = 0; hh < 2; ++hh)
            #pragma unroll
            for (int g = 0; g < 4; ++g) ag[hh][g] = zz4;
        #pragma unroll
        for (int g = 0; g < 4; ++g)
            #pragma unroll
            for (int hh = 0; hh < 2; ++hh) {
                int nt = g * 8 + 2 * w + hh;
                #pragma unroll
                for (int ks = 0; ks < 6; ++ks) {
                    bf16x8 bfr = pkE[(ks * 32 + nt) * 64 + lane];
                    ag[hh][g] = __builtin_amdgcn_mfma_f32_16x16x32_bf16(gA[ks], bfr, ag[hh][g], 0, 0, 0);
                }
            }

        // in-register LSTM cell + social injection; write new h (bf16, swizzled)
        #pragma unroll
        for (int hh = 0; hh < 2; ++hh)
            #pragma unroll
            for (int rg = 0; rg < 4; ++rg) {
                int a = q * 4 + rg;
                float gi = sigm(ag[hh][0][rg] + bG[hh][0]);
                float gf = sigm(ag[hh][1][rg] + bG[hh][1]);
                float gg = tanhp(ag[hh][2][rg] + bG[hh][2]);
                float go = sigm(ag[hh][3][rg] + bG[hh][3]);
                cst[hh][rg] = gf * cst[hh][rg] + gi * gg;
                float hn = go * tanhp(cst[hh][rg]);
                float s = fmaxf(ms[hh][rg] + hpA[hh][rg] + sbv[hh], 0.f);
                hn += 0.3f * s;
                int hidx = (2 * w + hh) * 16 + r16;
                *(short*)((char*)hw + a * 256 + ((hidx * 2) ^ ((a & 7) << 4))) = (short)f2bf(hn);
            }
        __syncthreads();
        pp ^= 1;
    }

    // ===================== DECODER =====================
    // hpE = h_enc @ WT (fixed), kept in registers
    f32x4 hpE[2] = {zz4, zz4};
    {
        const short* hb = hbf[pp];
        #pragma unroll
        for (int ks = 0; ks < 4; ++ks) {
            bf16x8 af = *(const bf16x8*)((const char*)hb + r16 * 256 +
                          (((ks * 32 + q * 8) * 2) ^ ((r16 & 7) << 4)));
            #pragma unroll
            for (int hh = 0; hh < 2; ++hh) {
                bf16x8 bfr = pkT[(ks * 8 + 2 * w + hh) * 64 + lane];
                hpE[hh] = __builtin_amdgcn_mfma_f32_16x16x32_bf16(af, bfr, hpE[hh], 0, 0, 0);
            }
        }
    }
    #pragma unroll
    for (int hh = 0; hh < 2; ++hh)
        #pragma unroll
        for (int g = 0; g < 4; ++g) {
            int col = g * 128 + (2 * w + hh) * 16 + r16;
            bG[hh][g] = dBih[col] + dBhh[col];
        }
    if (j < 32) cur[j >> 1][j & 1] = 0.f;
    __syncthreads();

    #pragma unroll 1
    for (int st = 0; st < TPR; ++st) {
        // ---- phase A: emb(cur) + pos_feat(-cur) ----
        #pragma unroll
        for (int s2 = 0; s2 < 4; ++s2) {
            int a = w + s2 * 4;
            float cx = cur[a][0], cy = cur[a][1];
            float xe = fmaxf(cx * dw0 + cy * dw1 + dbv, 0.f);
            *(short*)((char*)embb + a * 128 + ((lane * 2) ^ ((a & 7) << 4))) = (short)f2bf(xe);
            float vp = fmaxf(pbb - cx * pwa - cy * pwc, 0.f);
            *(short*)((char*)pfdb + a * 128 + ((lane * 2) ^ ((a & 7) << 4))) = (short)f2bf(vp);
        }
        __syncthreads();

        // ---- phase B1: social (single M-tile) ----
        const short* hb = hbf[pp];
        short* hw = hbf[pp ^ 1];
        f32x4 sa[2] = {zz4, zz4};
        #pragma unroll
        for (int ks = 0; ks < 2; ++ks) {
            bf16x8 af = *(const bf16x8*)((const char*)pfdb + r16 * 128 +
                          (((ks * 32 + q * 8) * 2) ^ ((r16 & 7) << 4)));
            #pragma unroll
            for (int hh = 0; hh < 2; ++hh)
                sa[hh] = __builtin_amdgcn_mfma_f32_16x16x32_bf16(af, wbf[ks][hh], sa[hh], 0, 0, 0);
        }
        #pragma unroll
        for (int hh = 0; hh < 2; ++hh)
            #pragma unroll
            for (int rg = 0; rg < 4; ++rg) {
                int a = q * 4 + rg;
                float cx = cur[a][0], cy = cur[a][1];
                bool vd = (cx * cx + cy * cy <= 4.f) && (maskb[a] != 0);
                float z = sa[hh][rg] + hpE[hh][rg] + sbv[hh];
                float sv = vd ? fmaxf(z, 0.f) : 0.f;
                int hidx = (2 * w + hh) * 16 + r16;
                *(short*)((char*)socb + a * 256 + ((hidx * 2) ^ ((a & 7) << 4))) = (short)f2bf(sv);
            }
        __syncthreads();

        // ---- phase B2: gates = [emb | soc | h] @ W ----
        bf16x8 dA[10];
        #pragma unroll
        for (int ks = 0; ks < 2; ++ks)
            dA[ks] = *(const bf16x8*)((const char*)embb + r16 * 128 +
                       (((ks * 32 + q * 8) * 2) ^ ((r16 & 7) << 4)));
        #pragma unroll
        for (int ks = 0; ks < 4; ++ks)
            dA[2 + ks] = *(const bf16x8*)((const char*)socb + r16 * 256 +
                       (((ks * 32 + q * 8) * 2) ^ ((r16 & 7) << 4)));
        #pragma unroll
        for (int ks = 0; ks < 4; ++ks)
            dA[6 + ks] = *(const bf16x8*)((const char*)hb + r16 * 256 +
                       (((ks * 32 + q * 8) * 2) ^ ((r16 & 7) << 4)));
        f32x4 ag[2][4];
        #pragma unroll
        for (int hh = 0; hh < 2; ++hh)
            #pragma unroll
            for (int g = 0; g < 4; ++g) ag[hh][g] = zz4;
        #pragma unroll
        for (int g = 0; g < 4; ++g)
            #pragma unroll
            for (int hh = 0; hh < 2; ++hh) {
                int nt = g * 8 + 2 * w + hh;
                #pragma unroll
                for (int ks = 0; ks < 10; ++ks) {
                    bf16x8 bfr = pkD[(ks * 32 + nt) * 64 + lane];
                    ag[hh][g] = __builtin_amdgcn_mfma_f32_16x16x32_bf16(dA[ks], bfr, ag[hh][g], 0, 0, 0);
                }
            }
        #pragma unroll
        for (int hh = 0; hh < 2; ++hh)
            #pragma unroll
            for (int rg = 0; rg < 4; ++rg) {
                int a = q * 4 + rg;
                float gi = sigm(ag[hh][0][rg] + bG[hh][0]);
                float gf = sigm(ag[hh][1][rg] + bG[hh][1]);
                float gg = tanhp(ag[hh][2][rg] + bG[hh][2]);
                float go = sigm(ag[hh][3][rg] + bG[hh][3]);
                cst[hh][rg] = gf * cst[hh][rg] + gi * gg;
                float hn = go * tanhp(cst[hh][rg]);
                int hidx = (2 * w + hh) * 16 + r16;
                *(short*)((char*)hw + a * 256 + ((hidx * 2) ^ ((a & 7) << 4))) = (short)f2bf(hn);
            }
        __syncthreads();
        pp ^= 1;

        // ---- phase C: outputs (mu feeds cur) ----
        if (j < 80) {
            int a = j / 5, p5 = j % 5;
            const char* hnb = (const char*)hbf[pp];
            float r = outB[p5];
            #pragma unroll
            for (int k0 = 0; k0 < 128; k0 += 8) {
                bf16x8 hv = *(const bf16x8*)(hnb + a * 256 + ((k0 * 2) ^ ((a & 7) << 4)));
                #pragma unroll
                for (int i = 0; i < 8; ++i)
                    r = fmaf(bf2f((unsigned short)hv[i]), outW[(k0 + i) * 5 + p5], r);
            }
            int n = n0 + a;
            if (p5 < 2) {
                cur[a][p5] = r;
                out[n * 24 + st * 2 + p5] = r + origin[a][p5];
            } else if (p5 < 4) {
                out[196608 + n * 24 + st * 2 + (p5 - 2)] = __expf(fminf(fmaxf(r, -4.f), 4.f));
            } else {
                out[393216 + n * 12 + st] = tanhp(r);
            }
        }
        __syncthreads();
    }
}

extern "C" void kernel_launch(void* const* d_in, const int* in_sizes, int n_in,
                              void* d_out, int out_size, void* d_ws, size_t ws_size,
                              hipStream_t stream) {
    const float* obs    = (const float*)d_in[0];
    const float* nb_obs = (const float*)d_in[1];
    const void*  nb_mask= d_in[2];
    const float* weW    = (const float*)d_in[3];
    const float* web    = (const float*)d_in[4];
    const float* encWih = (const float*)d_in[5];
    const float* encWhh = (const float*)d_in[6];
    const float* encBih = (const float*)d_in[7];
    const float* encBhh = (const float*)d_in[8];
    const float* pW     = (const float*)d_in[9];
    const float* pb     = (const float*)d_in[10];
    const float* sW     = (const float*)d_in[11];
    const float* sbv    = (const float*)d_in[12];
    const float* wdW    = (const float*)d_in[13];
    const float* wdb    = (const float*)d_in[14];
    const float* decWih = (const float*)d_in[15];
    const float* decWhh = (const float*)d_in[16];
    const float* decBih = (const float*)d_in[17];
    const float* decBhh = (const float*)d_in[18];
    const float* outW   = (const float*)d_in[19];
    const float* outB   = (const float*)d_in[20];
    float* out = (float*)d_out;
    unsigned short* pkw = (unsigned short*)d_ws;

    pack_w<<<(PK_TOT + 255) / 256, 256, 0, stream>>>(encWih, encWhh, decWih, decWhh, sW, pkw);
    slstm<<<N_AG / GA, BLK, 0, stream>>>(obs, nb_obs, nb_mask, weW, web,
        encBih, encBhh, pW, pb, sbv, wdW, wdb, decBih, decBhh, outW, outB, pkw, out);
}

// Round 5
// 394.871 us; speedup vs baseline: 14.1178x; 2.1725x over previous
//
#include <hip/hip_runtime.h>
#include <math.h>

typedef short bf16x8 __attribute__((ext_vector_type(8)));
typedef float f32x4  __attribute__((ext_vector_type(4)));

#define N_AG 8192
#define GA   16
#define BLK  512
#define TOB  8
#define TPR  12

// packed bf16 weight regions (offsets in shorts, inside d_ws)
#define PK_ENC 0
#define PK_DEC 98304            // + 6*32*512  (encoder gates)
#define PK_WB  262144           // +10*32*512  (decoder gates)
#define PK_WT  270336           // + 2*8*512   (sW pos-feat rows 128..191)
#define PK_TOT 286720           // + 4*8*512   (sW h rows 0..127)

__device__ __forceinline__ unsigned short f2bf(float f) {
    unsigned u = __float_as_uint(f);
    return (unsigned short)((u + 0x7FFFu + ((u >> 16) & 1u)) >> 16);   // RNE
}
__device__ __forceinline__ float bf2f(unsigned short s) {
    return __uint_as_float(((unsigned)s) << 16);
}
__device__ __forceinline__ float sigm(float x) { return 1.f / (1.f + __expf(-x)); }
__device__ __forceinline__ float tanhp(float x) {
    x = fminf(fmaxf(x, -15.f), 15.f);
    float e = __expf(2.f * x);
    return (e - 1.f) / (e + 1.f);
}

// Pack gate/social weights into per-MFMA-fragment bf16 blobs:
// frag(ks,nt) = 64 lanes x 8 shorts; element (l,i) = W[k][col],
// k = ks*32 + (l>>4)*8 + i, col = (nt>>3)*128 + (nt&7)*16 + (l&15)   (gates)
__global__ void pack_w(const float* __restrict__ eWih, const float* __restrict__ eWhh,
                       const float* __restrict__ dWih, const float* __restrict__ dWhh,
                       const float* __restrict__ sW, unsigned short* __restrict__ pk)
{
    for (int idx = blockIdx.x * blockDim.x + threadIdx.x; idx < PK_TOT;
         idx += gridDim.x * blockDim.x) {
        float v;
        if (idx < PK_DEC) {                       // encoder gates: ks 0-1 emb, 2-5 h
            int ks = idx >> 14, rem = idx & 16383;
            int nt = rem >> 9, l = (rem >> 3) & 63, i = rem & 7;
            int klo = ((l >> 4) << 3) + i;
            int col = (nt >> 3) * 128 + (nt & 7) * 16 + (l & 15);
            v = (ks < 2) ? eWih[(ks * 32 + klo) * 512 + col]
                         : eWhh[((ks - 2) * 32 + klo) * 512 + col];
        } else if (idx < PK_WB) {                 // decoder gates: ks 0-1 emb, 2-5 soc, 6-9 h
            int t = idx - PK_DEC;
            int ks = t >> 14, rem = t & 16383;
            int nt = rem >> 9, l = (rem >> 3) & 63, i = rem & 7;
            int klo = ((l >> 4) << 3) + i;
            int col = (nt >> 3) * 128 + (nt & 7) * 16 + (l & 15);
            if (ks < 2)      v = dWih[(ks * 32 + klo) * 512 + col];
            else if (ks < 6) v = dWih[(64 + (ks - 2) * 32 + klo) * 512 + col];
            else             v = dWhh[((ks - 6) * 32 + klo) * 512 + col];
        } else if (idx < PK_WT) {                 // Wb = sW rows 128..191 (pos-feat part), ks<2
            int t = idx - PK_WB;
            int ks = t >> 12, rem = t & 4095;
            int nt = rem >> 9, l = (rem >> 3) & 63, i = rem & 7;
            int klo = ((l >> 4) << 3) + i;
            v = sW[(128 + ks * 32 + klo) * 128 + nt * 16 + (l & 15)];
        } else {                                  // WT = sW rows 0..127 (h part), ks<4
            int t = idx - PK_WT;
            int ks = t >> 12, rem = t & 4095;
            int nt = rem >> 9, l = (rem >> 3) & 63, i = rem & 7;
            int klo = ((l >> 4) << 3) + i;
            v = sW[(ks * 32 + klo) * 128 + nt * 16 + (l & 15)];
        }
        pk[idx] = f2bf(v);
    }
}

__global__ __launch_bounds__(BLK, 4)
void slstm(const float* __restrict__ obs, const float* __restrict__ nb_obs,
           const void* __restrict__ nb_mask,
           const float* __restrict__ weW, const float* __restrict__ web,
           const float* __restrict__ eBih, const float* __restrict__ eBhh,
           const float* __restrict__ pW, const float* __restrict__ pb,
           const float* __restrict__ sb,
           const float* __restrict__ wdW, const float* __restrict__ wdb,
           const float* __restrict__ dBih, const float* __restrict__ dBhh,
           const float* __restrict__ outW, const float* __restrict__ outB,
           const unsigned short* __restrict__ pk,
           float* __restrict__ out)
{
    __shared__ __align__(16) float obsrel[TOB][GA][2];
    __shared__ float origin[GA][2];
    __shared__ __align__(16) float nblast[GA][32][2];
    __shared__ __align__(16) float rel2[GA][32][2];
    __shared__ unsigned vmask[GA];
    __shared__ int maskb[GA];
    __shared__ int detf;
    __shared__ __align__(16) short hbf[2][GA * 128];   // bf16 h, XOR-swizzled, ping-pong
    __shared__ __align__(16) short embb[GA * 64];      // bf16 emb, swizzled
    __shared__ __align__(16) short socb[GA * 128];     // bf16 decoder social, swizzled
    __shared__ __align__(16) short pfdb[GA * 64];      // bf16 decoder pos_feat, swizzled
    __shared__ __align__(16) short pft[256 * 64];      // 32 KB: encoder pos_feat tile (16a x 16nb)
    __shared__ float cur[GA][2];

    const int j    = threadIdx.x;
    const int lane = j & 63;
    const int w    = j >> 6;          // wave 0..7, owns h-cols [16w, 16w+16)
    const int q    = lane >> 4;
    const int r16  = lane & 15;
    const int n0   = blockIdx.x * GA;

    // ---------- init ----------
    if (j < GA) maskb[j] = 0;
    if (j == 0) detf = 0;
    __syncthreads();
    {
        const unsigned* mw = (const unsigned*)nb_mask;
        unsigned w0 = mw[j], w1 = mw[BLK + j];
        int f = 0;
        if (w0 > 1u || w1 > 1u) f |= 1;
        if ((w0 != 0u && w0 != 0x3F800000u) || (w1 != 0u && w1 != 0x3F800000u)) f |= 2;
        if (f) atomicOr(&detf, f);
    }
    __syncthreads();
    const int det = detf;
    {
        int a = j >> 5, i2 = j & 31, gi = (n0 + a) * 32 + i2;
        int bit;
        if (!(det & 1))      bit = ((const int*)nb_mask)[gi] != 0;
        else if (!(det & 2)) bit = (((const float*)nb_mask)[gi] != 0.f);
        else                 bit = ((const unsigned char*)nb_mask)[gi] != 0;
        if (bit) atomicOr(&maskb[a], 1 << i2);
    }
    if (j < 128) {
        int t = j >> 4, a = j & 15;
        float o0 = obs[(n0 + a) * 16 + 14], o1 = obs[(n0 + a) * 16 + 15];
        obsrel[t][a][0] = obs[(n0 + a) * 16 + t * 2]     - o0;
        obsrel[t][a][1] = obs[(n0 + a) * 16 + t * 2 + 1] - o1;
        if (t == 0) { origin[a][0] = o0; origin[a][1] = o1; }
    }
    {
        int a = j >> 5, i2 = j & 31;
        const float* nb = nb_obs + ((size_t)((n0 + a) * 32 + i2)) * 16 + 14;
        nblast[a][i2][0] = nb[0];
        nblast[a][i2][1] = nb[1];
    }
    ((int4*)hbf)[j] = make_int4(0, 0, 0, 0);   // zero both h buffers (8 KB)

    // per-lane constants (slim)
    const int e2 = (j & 31) * 2;                 // pft col pair
    const float pca0 = pW[e2],      pca1 = pW[e2 + 1];
    const float pcc0 = pW[64 + e2], pcc1 = pW[64 + e2 + 1];
    const float pcb0 = pb[e2],      pcb1 = pb[e2 + 1];
    const float ew0 = weW[lane], ew1 = weW[64 + lane], ebv = web[lane];
    const float dw0 = wdW[lane], dw1 = wdW[64 + lane], dbv = wdb[lane];
    const float pwa = pW[lane], pwc = pW[64 + lane], pbb = pb[lane];
    const float sbv = sb[w * 16 + r16];
    float bG[4];
    #pragma unroll
    for (int g = 0; g < 4; ++g) {
        int col = g * 128 + w * 16 + r16;
        bG[g] = eBih[col] + eBhh[col];
    }
    const bf16x8* pkE = (const bf16x8*)(pk + PK_ENC);
    const bf16x8* pkD = (const bf16x8*)(pk + PK_DEC);
    const bf16x8* pkB = (const bf16x8*)(pk + PK_WB);
    const bf16x8* pkT = (const bf16x8*)(pk + PK_WT);
    bf16x8 wbf[2];                               // social Wb frags for this wave's 16 cols
    #pragma unroll
    for (int ks = 0; ks < 2; ++ks)
        wbf[ks] = pkB[(ks * 8 + w) * 64 + lane];

    float cst[4];                                // cell state: agent=q*4+rg, col=w*16+r16
    #pragma unroll
    for (int rg = 0; rg < 4; ++rg) cst[rg] = 0.f;

    const f32x4 zz4 = {0.f, 0.f, 0.f, 0.f};
    int pp = 0;
    __syncthreads();

    // ===================== ENCODER =====================
    #pragma unroll 1
    for (int t = 0; t < TOB; ++t) {
        // ---- A0: rel/valid (ballot) + emb ----
        {
            int a = j >> 5, i2 = j & 31;
            const float* nb = nb_obs + ((size_t)((n0 + a) * 32 + i2)) * 16 + t * 2;
            float rx = nb[0] - nblast[a][i2][0] - obsrel[t][a][0];
            float ry = nb[1] - nblast[a][i2][1] - obsrel[t][a][1];
            rel2[a][i2][0] = rx; rel2[a][i2][1] = ry;
            bool ok = (rx * rx + ry * ry <= 4.f) && ((maskb[a] >> i2) & 1);
            unsigned long long b = __ballot(ok);
            if ((lane & 31) == 0) vmask[2 * w + (lane >> 5)] = (unsigned)(b >> (lane & 32));
        }
        #pragma unroll
        for (int s = 0; s < 2; ++s) {
            int a = w + 8 * s;
            float x = fmaxf(obsrel[t][a][0] * ew0 + obsrel[t][a][1] * ew1 + ebv, 0.f);
            *(short*)((char*)embb + a * 128 + ((lane * 2) ^ ((a & 7) << 4))) = (short)f2bf(x);
        }
        __syncthreads();

        float ms[4];
        #pragma unroll
        for (int rg = 0; rg < 4; ++rg) ms[rg] = -3e38f;
        f32x4 hpA = zz4;
        f32x4 ag[4];
        #pragma unroll
        for (int g = 0; g < 4; ++g) ag[g] = zz4;
        const short* hb = hbf[pp];
        short* hw = hbf[pp ^ 1];

        #pragma unroll 1
        for (int Mt = 0; Mt < 2; ++Mt) {
            // ---- pft fill for this 16-neighbor chunk ----
            {
                int rw = j >> 5;
                #pragma unroll 2
                for (int s = 0; s < 16; ++s) {
                    int row = rw + 16 * s;          // row = a*16 + il
                    int a = row >> 4, il = row & 15;
                    float rx = rel2[a][Mt * 16 + il][0], ry = rel2[a][Mt * 16 + il][1];
                    float v0 = fmaxf(rx * pca0 + ry * pcc0 + pcb0, 0.f);
                    float v1 = fmaxf(rx * pca1 + ry * pcc1 + pcb1, 0.f);
                    unsigned u = (unsigned)f2bf(v0) | ((unsigned)f2bf(v1) << 16);
                    *(unsigned*)((char*)pft + row * 128 + ((e2 * 2) ^ ((row & 7) << 4))) = u;
                }
            }
            __syncthreads();

            // ---- compute phase ----
            if (Mt == 0) {
                // hp = h @ WT (this wave's 16 cols)
                #pragma unroll
                for (int ks = 0; ks < 4; ++ks) {
                    bf16x8 af = *(const bf16x8*)((const char*)hb + r16 * 256 +
                                  (((ks * 32 + q * 8) * 2) ^ ((r16 & 7) << 4)));
                    bf16x8 bfr = pkT[(ks * 8 + w) * 64 + lane];
                    hpA = __builtin_amdgcn_mfma_f32_16x16x32_bf16(af, bfr, hpA, 0, 0, 0);
                }
                // gates = [emb | h] @ W, ks-outer to keep regs small
                #pragma unroll 2
                for (int ks = 0; ks < 6; ++ks) {
                    bf16x8 af = (ks < 2)
                        ? *(const bf16x8*)((const char*)embb + r16 * 128 +
                              (((ks * 32 + q * 8) * 2) ^ ((r16 & 7) << 4)))
                        : *(const bf16x8*)((const char*)hb + r16 * 256 +
                              ((((ks - 2) * 32 + q * 8) * 2) ^ ((r16 & 7) << 4)));
                    #pragma unroll
                    for (int g = 0; g < 4; ++g) {
                        bf16x8 bfr = pkE[(ks * 32 + g * 8 + w) * 64 + lane];
                        ag[g] = __builtin_amdgcn_mfma_f32_16x16x32_bf16(af, bfr, ag[g], 0, 0, 0);
                    }
                }
            }
            // social for this chunk: per agent 2 mfma + masked max
            #pragma unroll 1
            for (int a4 = 0; a4 < 4; ++a4) {
                #pragma unroll
                for (int ar = 0; ar < 4; ++ar) {
                    int a = a4 * 4 + ar;
                    f32x4 ac = zz4;
                    #pragma unroll
                    for (int ks = 0; ks < 2; ++ks) {
                        bf16x8 af = *(const bf16x8*)((const char*)pft + (a * 16 + r16) * 128 +
                                      (((ks * 32 + q * 8) * 2) ^ ((r16 & 7) << 4)));
                        ac = __builtin_amdgcn_mfma_f32_16x16x32_bf16(af, wbf[ks], ac, 0, 0, 0);
                    }
                    unsigned vb = vmask[a];
                    float ml = -3e38f;
                    #pragma unroll
                    for (int rg = 0; rg < 4; ++rg) {
                        bool ok = (vb >> (Mt * 16 + q * 4 + rg)) & 1;
                        ml = fmaxf(ml, ok ? ac[rg] : -3e38f);
                    }
                    ml = fmaxf(ml, __shfl_xor(ml, 16));
                    ml = fmaxf(ml, __shfl_xor(ml, 32));
                    ms[ar] = fmaxf(ms[ar], (q == a4) ? ml : -3e38f);
                }
            }
            __syncthreads();   // pft consumed (Mt=0) / all done (Mt=1)
        }

        // cell update + social injection; write new h
        #pragma unroll
        for (int rg = 0; rg < 4; ++rg) {
            int a = q * 4 + rg;
            float gi = sigm(ag[0][rg] + bG[0]);
            float gf = sigm(ag[1][rg] + bG[1]);
            float gg = tanhp(ag[2][rg] + bG[2]);
            float go = sigm(ag[3][rg] + bG[3]);
            cst[rg] = gf * cst[rg] + gi * gg;
            float hn = go * tanhp(cst[rg]) + 0.3f * fmaxf(ms[rg] + hpA[rg] + sbv, 0.f);
            int hidx = w * 16 + r16;
            *(short*)((char*)hw + a * 256 + ((hidx * 2) ^ ((a & 7) << 4))) = (short)f2bf(hn);
        }
        __syncthreads();
        pp ^= 1;
    }

    // ===================== DECODER =====================
    f32x4 hpE = zz4;
    {
        const short* hb = hbf[pp];
        #pragma unroll
        for (int ks = 0; ks < 4; ++ks) {
            bf16x8 af = *(const bf16x8*)((const char*)hb + r16 * 256 +
                          (((ks * 32 + q * 8) * 2) ^ ((r16 & 7) << 4)));
            bf16x8 bfr = pkT[(ks * 8 + w) * 64 + lane];
            hpE = __builtin_amdgcn_mfma_f32_16x16x32_bf16(af, bfr, hpE, 0, 0, 0);
        }
    }
    #pragma unroll
    for (int g = 0; g < 4; ++g) {
        int col = g * 128 + w * 16 + r16;
        bG[g] = dBih[col] + dBhh[col];
    }
    if (j < 32) cur[j >> 1][j & 1] = 0.f;
    __syncthreads();

    #pragma unroll 1
    for (int st = 0; st < TPR; ++st) {
        // ---- A: emb(cur) + pos_feat(-cur) ----
        #pragma unroll
        for (int s = 0; s < 2; ++s) {
            int a = w + 8 * s;
            float cx = cur[a][0], cy = cur[a][1];
            float xe = fmaxf(cx * dw0 + cy * dw1 + dbv, 0.f);
            *(short*)((char*)embb + a * 128 + ((lane * 2) ^ ((a & 7) << 4))) = (short)f2bf(xe);
            float vp = fmaxf(pbb - cx * pwa - cy * pwc, 0.f);
            *(short*)((char*)pfdb + a * 128 + ((lane * 2) ^ ((a & 7) << 4))) = (short)f2bf(vp);
        }
        __syncthreads();

        // ---- B1: social (single M-tile of 16 agents) ----
        const short* hb = hbf[pp];
        short* hw = hbf[pp ^ 1];
        {
            f32x4 sa = zz4;
            #pragma unroll
            for (int ks = 0; ks < 2; ++ks) {
                bf16x8 af = *(const bf16x8*)((const char*)pfdb + r16 * 128 +
                              (((ks * 32 + q * 8) * 2) ^ ((r16 & 7) << 4)));
                sa = __builtin_amdgcn_mfma_f32_16x16x32_bf16(af, wbf[ks], sa, 0, 0, 0);
            }
            #pragma unroll
            for (int rg = 0; rg < 4; ++rg) {
                int a = q * 4 + rg;
                float cx = cur[a][0], cy = cur[a][1];
                bool vd = (cx * cx + cy * cy <= 4.f) && (maskb[a] != 0);
                float z = sa[rg] + hpE[rg] + sbv;
                float sv = vd ? fmaxf(z, 0.f) : 0.f;
                int hidx = w * 16 + r16;
                *(short*)((char*)socb + a * 256 + ((hidx * 2) ^ ((a & 7) << 4))) = (short)f2bf(sv);
            }
        }
        __syncthreads();

        // ---- B2: gates = [emb | soc | h] @ W, ks-outer ----
        f32x4 ag[4];
        #pragma unroll
        for (int g = 0; g < 4; ++g) ag[g] = zz4;
        #pragma unroll 2
        for (int ks = 0; ks < 10; ++ks) {
            bf16x8 af;
            if (ks < 2)
                af = *(const bf16x8*)((const char*)embb + r16 * 128 +
                       (((ks * 32 + q * 8) * 2) ^ ((r16 & 7) << 4)));
            else if (ks < 6)
                af = *(const bf16x8*)((const char*)socb + r16 * 256 +
                       ((((ks - 2) * 32 + q * 8) * 2) ^ ((r16 & 7) << 4)));
            else
                af = *(const bf16x8*)((const char*)hb + r16 * 256 +
                       ((((ks - 6) * 32 + q * 8) * 2) ^ ((r16 & 7) << 4)));
            #pragma unroll
            for (int g = 0; g < 4; ++g) {
                bf16x8 bfr = pkD[(ks * 32 + g * 8 + w) * 64 + lane];
                ag[g] = __builtin_amdgcn_mfma_f32_16x16x32_bf16(af, bfr, ag[g], 0, 0, 0);
            }
        }
        #pragma unroll
        for (int rg = 0; rg < 4; ++rg) {
            int a = q * 4 + rg;
            float gi = sigm(ag[0][rg] + bG[0]);
            float gf = sigm(ag[1][rg] + bG[1]);
            float gg = tanhp(ag[2][rg] + bG[2]);
            float go = sigm(ag[3][rg] + bG[3]);
            cst[rg] = gf * cst[rg] + gi * gg;
            float hn = go * tanhp(cst[rg]);
            int hidx = w * 16 + r16;
            *(short*)((char*)hw + a * 256 + ((hidx * 2) ^ ((a & 7) << 4))) = (short)f2bf(hn);
        }
        __syncthreads();
        pp ^= 1;

        // ---- C: outputs (mu feeds cur) ----
        if (j < 80) {
            int a = j / 5, p5 = j % 5;
            const char* hnb = (const char*)hbf[pp];
            float r = outB[p5];
            #pragma unroll
            for (int k0 = 0; k0 < 128; k0 += 8) {
                bf16x8 hv = *(const bf16x8*)(hnb + a * 256 + ((k0 * 2) ^ ((a & 7) << 4)));
                #pragma unroll
                for (int i = 0; i < 8; ++i)
                    r = fmaf(bf2f((unsigned short)hv[i]), outW[(k0 + i) * 5 + p5], r);
            }
            int n = n0 + a;
            if (p5 < 2) {
                cur[a][p5] = r;
                out[n * 24 + st * 2 + p5] = r + origin[a][p5];
            } else if (p5 < 4) {
                out[196608 + n * 24 + st * 2 + (p5 - 2)] = __expf(fminf(fmaxf(r, -4.f), 4.f));
            } else {
                out[393216 + n * 12 + st] = tanhp(r);
            }
        }
        __syncthreads();
    }
}

extern "C" void kernel_launch(void* const* d_in, const int* in_sizes, int n_in,
                              void* d_out, int out_size, void* d_ws, size_t ws_size,
                              hipStream_t stream) {
    const float* obs    = (const float*)d_in[0];
    const float* nb_obs = (const float*)d_in[1];
    const void*  nb_mask= d_in[2];
    const float* weW    = (const float*)d_in[3];
    const float* web    = (const float*)d_in[4];
    const float* encWih = (const float*)d_in[5];
    const float* encWhh = (const float*)d_in[6];
    const float* encBih = (const float*)d_in[7];
    const float* encBhh = (const float*)d_in[8];
    const float* pW     = (const float*)d_in[9];
    const float* pb     = (const float*)d_in[10];
    const float* sW     = (const float*)d_in[11];
    const float* sbv    = (const float*)d_in[12];
    const float* wdW    = (const float*)d_in[13];
    const float* wdb    = (const float*)d_in[14];
    const float* decWih = (const float*)d_in[15];
    const float* decWhh = (const float*)d_in[16];
    const float* decBih = (const float*)d_in[17];
    const float* decBhh = (const float*)d_in[18];
    const float* outW   = (const float*)d_in[19];
    const float* outB   = (const float*)d_in[20];
    float* out = (float*)d_out;
    unsigned short* pkw = (unsigned short*)d_ws;

    pack_w<<<(PK_TOT + 255) / 256, 256, 0, stream>>>(encWih, encWhh, decWih, decWhh, sW, pkw);
    slstm<<<N_AG / GA, BLK, 0, stream>>>(obs, nb_obs, nb_mask, weW, web,
        encBih, encBhh, pW, pb, sbv, wdW, wdb, decBih, decBhh, outW, outB, pkw, out);
}